// Round 9
// baseline (220.465 us; speedup 1.0000x reference)
//
#include <hip/hip_runtime.h>

// LSTM B=8192, T=168, P=16, H=24, gates [i,f,g,o].
// Round-17: r12 grid/occupancy x r14 global-x path (no LDS x-staging).
//  - r16 post-mortem: Pade moved issue from trans pipe (80% hidden) to VALU
//    pipe (80% exposed): step 1405->1727. Cell math reverted to exp2 form.
//  - Cross-round fit: throughput = 32 batches/CU/step (fixed); only lever is
//    step time. r14's per-CHAIN-step was 1023 vs r12's 1405; body delta =
//    x from global regs instead of per-step LDS reads. Post-barrier LDS
//    burst (16 waves x 2 ds_read_b128 = 32KB/CU/step ~ 400 pipe-cyc) is the
//    hypothesized un-fillable stall component; x-side is half of it and
//    pure redundancy (all waves read identical x).
//  - This round: 512 blocks x 8 waves (2 blocks/CU, proven frame), wave w
//    = tile w, 1 cell/lane, self-aligned exchange (write hx[q][n][w] b16,
//    read half8 b128). x: 2-step register prefetch from global (L1 serves
//    8x intra-CU reuse). soft_barrier (lgkmcnt only, no vmcnt drain) keeps
//    prefetches in flight across the step barrier. LDS = 2KB hx + epilogue.
//  - Cell math identical to r12 (fused denominator, 7 trans/cell).

#define T_STEPS 168
#define P_FEAT  16
#define NB      16   // batches per block (one chain)

typedef _Float16 half8 __attribute__((ext_vector_type(8)));
typedef float    f32x4 __attribute__((ext_vector_type(4)));

__device__ __forceinline__ float rcp_fast(float x) {
#if __has_builtin(__builtin_amdgcn_rcpf)
    return __builtin_amdgcn_rcpf(x);
#else
    return 1.0f / x;
#endif
}
__device__ __forceinline__ float exp2_fast(float x) {
#if __has_builtin(__builtin_amdgcn_exp2f)
    return __builtin_amdgcn_exp2f(x);
#else
    return exp2f(x);
#endif
}
__device__ __forceinline__ float tanh_f(float x) {
    return 1.0f - 2.0f * rcp_fast(1.0f + exp2_fast(x * 2.88539008f));
}
// lgkmcnt(0) + s_barrier, WITHOUT the vmcnt(0) drain __syncthreads adds:
// global x prefetches stay in flight across the step barrier.
__device__ __forceinline__ void soft_barrier() {
    asm volatile("s_waitcnt lgkmcnt(0)\n\ts_barrier" ::: "memory");
}

__global__ __launch_bounds__(512, 2) void lstm_gx(
    const float* __restrict__ x,
    const float* __restrict__ W_ih,
    const float* __restrict__ W_hh,
    const float* __restrict__ b_ih,
    const float* __restrict__ b_hh,
    const float* __restrict__ W_lin,
    const float* __restrict__ b_lin,
    float* __restrict__ out)
{
    __shared__ __align__(16) _Float16 hx[2][4][NB][8];   // 2048 B ping-pong h
    __shared__ __align__(16) float    thbuf[NB][24];     // 1536 B epilogue

    const int tid  = threadIdx.x;
    const int w    = tid >> 6;       // wave 0..7: tile mt = w
    const int lane = tid & 63;
    const int n    = lane & 15;      // batch col (B/C) == row p supplied (A)
    const int q    = lane >> 4;      // k-chunk (A/B) == output quad (C)
    const int batch = blockIdx.x * NB + n;

    // ---- A-fragments for this wave's tile (mt = w), straight from global ----
    // tile row p: gate p%4 of unit 8*(p/4)+w; rows p>=12 zero.
    // A-frag layout: A[m=lane&15][k=quad*8+j].
    half8 A1, A2;
    f32x4 biasf;
    {
        const int p  = n;
        const bool vrow = (p < 12);
        const int grow = vrow ? ((p & 3) * 24 + 8 * (p >> 2) + w) : 0;
        #pragma unroll
        for (int j = 0; j < 8; j++) {
            const int k = q * 8 + j;
            A1[j] = (vrow && k < 24) ? (_Float16)W_hh[grow * 24 + k] : (_Float16)0.0f;
            A2[j] = (vrow && k < 16) ? (_Float16)W_ih[grow * 16 + k] : (_Float16)0.0f;
        }
        #pragma unroll
        for (int r = 0; r < 4; r++) {
            const int u = 8 * q + w;    // lane (q,n) holds gates r of unit u (q<3)
            biasf[r] = (q < 3) ? (b_ih[r * 24 + u] + b_hh[r * 24 + u]) : 0.0f;
        }
    }
    // zero hx (both buffers; q=3 rows stay 0 forever = K-pad)
    {
        unsigned* hz = reinterpret_cast<unsigned*>(&hx[0][0][0][0]);   // 512 dwords
        if (tid < 512) hz[tid] = 0u;
    }
    __syncthreads();

    float c  = 0.0f;
    float hv = 0.0f;

    // per-lane global x row: q<2 lanes carry features 8q..8q+7
    const float* xrow = x + (size_t)batch * (T_STEPS * P_FEAT) + 8 * q;

    auto xload = [&](int t, float4& r0, float4& r1) {
        if (q < 2) {
            const float4* p = reinterpret_cast<const float4*>(xrow + (size_t)t * P_FEAT);
            r0 = p[0];
            r1 = p[1];
        }
    };
    auto mkB2 = [&](const float4& r0, const float4& r1) -> half8 {
        half8 b = {};
        if (q < 2) {
            b[0] = (_Float16)r0.x; b[1] = (_Float16)r0.y;
            b[2] = (_Float16)r0.z; b[3] = (_Float16)r0.w;
            b[4] = (_Float16)r1.x; b[5] = (_Float16)r1.y;
            b[6] = (_Float16)r1.z; b[7] = (_Float16)r1.w;
        }
        return b;
    };

    f32x4 gx;
    int bufp = 0;

    // x prefetch buffers (even/odd step parity): hold x(t+1) entering step t
    float4 xe0 = {0,0,0,0}, xe1 = {0,0,0,0};
    float4 xo0 = {0,0,0,0}, xo1 = {0,0,0,0};

    // ---- prologue: gx(0) + prefetch x(1), x(2) ----
    {
        float4 t00 = {0,0,0,0}, t01 = {0,0,0,0};
        xload(0, t00, t01);
        xload(1, xe0, xe1);
        xload(2, xo0, xo1);
        gx = __builtin_amdgcn_mfma_f32_16x16x32_f16(A2, mkB2(t00, t01), biasf, 0, 0, 0);
    }

    // one time-step; buf holds x(t+1); reload x(tload) for two intervals ahead
    auto one_t = [&](float4& b0, float4& b1, int tload) {
        // B1: element j = h of unit 8q+j for batch n (j written by wave j)
        const half8 B1 = *reinterpret_cast<const half8*>(&hx[bufp][q][n][0]);
        f32x4 g = __builtin_amdgcn_mfma_f32_16x16x32_f16(A1, B1, gx, 0, 0, 0);
        gx = __builtin_amdgcn_mfma_f32_16x16x32_f16(A2, mkB2(b0, b1), biasf, 0, 0, 0);
        xload(tload, b0, b1);          // refill for t+3 (stays in flight)
        // fused-denominator activations: 7 trans for this lane's cell
        //   c' = [c(1+Y)(1+Z) + (1+X)(Z-1)] * rcp((1+X)(1+Y)(1+Z))
        //   h  = (W-1) * rcp((1+V)(1+W)),  W = e^{2*min(c',18)}
        {
            const float Y  = exp2_fast(g[0] * -1.44269504f);  // i
            const float X  = exp2_fast(g[1] * -1.44269504f);  // f
            const float Z  = exp2_fast(g[2] *  2.88539008f);  // g
            const float V  = exp2_fast(g[3] * -1.44269504f);  // o
            const float ax = 1.0f + X;
            const float ay = 1.0f + Y;
            const float az = 1.0f + Z;
            const float num = c * ay * az + ax * (Z - 1.0f);
            const float cn  = num * rcp_fast(ax * ay * az);
            c = cn;
            const float W  = exp2_fast(fminf(cn, 18.0f) * 2.88539008f);
            hv = (W - 1.0f) * rcp_fast((1.0f + V) * (1.0f + W));
        }
        // publish own unit to the other buffer; q=3 stays zero (K-pad)
        if (q < 3) hx[1 - bufp][q][n][w] = (_Float16)hv;
        bufp ^= 1;
        soft_barrier();
    };

    for (int t = 0; t < T_STEPS; t += 2) {
        one_t(xe0, xe1, (t + 3 < T_STEPS) ? t + 3 : 0);
        one_t(xo0, xo1, (t + 4 < T_STEPS) ? t + 4 : 0);
    }

    // ---- epilogue: out[b][u] = b_lin[u] + sum_k tanh(h[k]) * W_lin[u][k] ----
    if (q < 3) thbuf[n][8 * q + w] = tanh_f(hv);
    __syncthreads();

    if (q < 3) {
        const int u = 8 * q + w;
        const float* wl = &W_lin[u * 24];
        float acc = b_lin[u];
        #pragma unroll
        for (int k = 0; k < 24; k++) acc = fmaf(thbuf[n][k], wl[k], acc);
        out[(size_t)batch * 24 + u] = acc;
    }
}

extern "C" void kernel_launch(void* const* d_in, const int* in_sizes, int n_in,
                              void* d_out, int out_size, void* d_ws, size_t ws_size,
                              hipStream_t stream) {
    const float* x     = (const float*)d_in[0];
    const float* W_ih  = (const float*)d_in[1];
    const float* W_hh  = (const float*)d_in[2];
    const float* b_ih  = (const float*)d_in[3];
    const float* b_hh  = (const float*)d_in[4];
    const float* W_lin = (const float*)d_in[5];
    const float* b_lin = (const float*)d_in[6];
    float* out = (float*)d_out;

    const int B = in_sizes[0] / (T_STEPS * P_FEAT);   // 8192
    dim3 grid(B / NB), block(512);                    // 512 blocks x 8 waves
    lstm_gx<<<grid, block, 0, stream>>>(x, W_ih, W_hh, b_ih, b_hh, W_lin, b_lin, out);
}

// Round 10
// 194.477 us; speedup vs baseline: 1.1336x; 1.1336x over previous
//
#include <hip/hip_runtime.h>

// LSTM B=8192, T=168, P=16, H=24, gates [i,f,g,o].
// Round-18: 6-tile zero-waste layout, 12-wave two-chain blocks.
//  - r17 post-mortem: per-step global x = 32 cache lines per load instr ->
//    VMEM pipe swamped (step 1844, VALUBusy down). LDS x-staging is right.
//  - Model: interval = per-SIMD issue + chain + convoy. r12: 4 waves/SIMD
//    x 180 = 720 issue, 25% of it pure q=3-lane waste (issue is per-wave).
//  - Fix: r13's 6-tile map on the barrier frame. Row rho of tile tau =
//    gate rho&3 of unit 6*(rho>>2)+tau (96 rows exact); B1 slot 8q+j =
//    unit 6q+j (j<6, j=6,7 pad). All 64 lanes carry a valid cell
//    (u = 6q+tau, batch n). Chain = 6 waves; block = 12 waves = 2 chains
//    (waves 0-5 chain A, 6-11 chain B). 256 blocks x 768 thr = 1 block/CU,
//    3 waves/SIMD balanced. Per-SIMD issue 720 -> 540 per interval
//    (2 chain-steps), trans pipe at its 336-cyc floor.
//  - Exchange self-aligned as ever: write hx[cc][q][n][tau] b16, read
//    half8 hx[cc][q][n][0..7] b128 (slots 6,7 stay zero).
//  - Cell math identical to r12 (fused denominator, 7 trans/cell); 6-tile
//    numerics already validated by r13 (same absmax).

#define T_STEPS 168
#define P_FEAT  16
#define TCH     84                 // t-chunk length (2 chunks)
#define NB      32                 // batches per block: 2 chains x 16
#define BPAD    24                 // f16 pad per batch (2-way banks)
#define BSTR    (TCH * 16 + BPAD)  // 1368 f16 per batch

typedef _Float16 half8 __attribute__((ext_vector_type(8)));
typedef _Float16 h2    __attribute__((ext_vector_type(2)));
typedef float    f32x4 __attribute__((ext_vector_type(4)));

__device__ __forceinline__ float rcp_fast(float x) {
#if __has_builtin(__builtin_amdgcn_rcpf)
    return __builtin_amdgcn_rcpf(x);
#else
    return 1.0f / x;
#endif
}
__device__ __forceinline__ float exp2_fast(float x) {
#if __has_builtin(__builtin_amdgcn_exp2f)
    return __builtin_amdgcn_exp2f(x);
#else
    return exp2f(x);
#endif
}
__device__ __forceinline__ float tanh_f(float x) {
    return 1.0f - 2.0f * rcp_fast(1.0f + exp2_fast(x * 2.88539008f));
}
__device__ __forceinline__ h2 pack2(float a, float b) {
    h2 r; r.x = (_Float16)a; r.y = (_Float16)b; return r;
}

__global__ __launch_bounds__(768, 3) void lstm_6t(
    const float* __restrict__ x,
    const float* __restrict__ W_ih,
    const float* __restrict__ W_hh,
    const float* __restrict__ b_ih,
    const float* __restrict__ b_hh,
    const float* __restrict__ W_lin,
    const float* __restrict__ b_lin,
    float* __restrict__ out)
{
    __shared__ __align__(16) _Float16 xs16[NB * BSTR];      // 87552 B (W-stage reused)
    __shared__ __align__(16) _Float16 hx[2][2][4][16][8];   //  4096 B ping-pong h
    __shared__ __align__(16) _Float16 zblk[16];             //    32 B zeros (B2 pad)
    __shared__ __align__(16) float    thbuf[2][16][25];     //  3200 B epilogue

    const int tid  = threadIdx.x;
    const int w    = tid >> 6;        // wave 0..11
    const int lane = tid & 63;
    const int n    = lane & 15;       // batch col (B/C) == row p supplied (A)
    const int q    = lane >> 4;       // k-chunk (A/B) == output row-quad (C)
    const int cc   = (w >= 6);        // chain 0 / 1
    const int tau  = w - 6 * cc;      // tile 0..5 within chain
    const int batch = blockIdx.x * NB + 16 * cc + n;

    // ---- one-time: stage fused W (f32) into xs16 space ----
    float* wstage = reinterpret_cast<float*>(xs16);         // 96*40 f32
    for (int idx = tid; idx < 96 * 40; idx += 768) {
        const int j = idx / 40;
        const int k = idx - j * 40;
        wstage[idx] = (k < 24) ? W_hh[j * 24 + k] : W_ih[j * 16 + (k - 24)];
    }
    __syncthreads();

    // ---- A-fragments for this wave's tile (6-tile map) ----
    // A row m=n: W row grow = gate (n&3) of unit 6*(n>>2)+tau.
    // A1 col j (slot 8q+j): W_hh[grow][6q+j] for j<6, pad j=6,7.
    // A2 col j: W_ih[grow][8q+j] for 8q+j<16 (q<2), else 0.
    half8 A1, A2;
    f32x4 biasf;
    {
        const int grow = (n & 3) * 24 + 6 * (n >> 2) + tau;
        #pragma unroll
        for (int j = 0; j < 8; j++) {
            A1[j] = (j < 6) ? (_Float16)wstage[grow * 40 + 6 * q + j] : (_Float16)0.0f;
            const int k = q * 8 + j;
            A2[j] = (k < 16) ? (_Float16)wstage[grow * 40 + 24 + k] : (_Float16)0.0f;
        }
        const int u = 6 * q + tau;    // this lane's unit (ALL lanes valid)
        #pragma unroll
        for (int r = 0; r < 4; r++)
            biasf[r] = b_ih[r * 24 + u] + b_hh[r * 24 + u];
    }
    // zero hx (both buffers; slots 6,7 stay 0 forever = K-pad) + zblk
    {
        unsigned* hz = reinterpret_cast<unsigned*>(&hx[0][0][0][0][0]);  // 1024 dw
        if (tid < 512) { hz[tid] = 0u; hz[tid + 512] = 0u; }
        if (tid < 8) reinterpret_cast<unsigned*>(zblk)[tid] = 0u;
    }
    __syncthreads();   // wstage dead; x staging reuses the space

    float c  = 0.0f;
    float hv = 0.0f;

    const float4* xsrc = reinterpret_cast<const float4*>(x)
                       + (size_t)(blockIdx.x * NB) * (T_STEPS * P_FEAT / 4);

    // B2 source: quads 0..1 read x halves, quads 2..3 the zero block
    const _Float16* xrowbase = (q < 2) ? &xs16[(16 * cc + n) * BSTR + q * 8] : zblk;
    const int xstep = (q < 2) ? 16 : 0;

    int bufp = 0;
    for (int ch = 0; ch < 2; ch++) {
        // stage NB x TCH x 16 f32 -> f16 (padded layout): 10752 float4, 14/thread
        for (int i = 0; i < 14; i++) {
            const int m   = tid + 768 * i;      // 0..10751
            const int b   = m / 336;            // 336 float4 per batch-chunk
            const int rem = m - b * 336;
            const float4 v = xsrc[(size_t)b * 672 + ch * 336 + rem];
            h2* dst = reinterpret_cast<h2*>(xs16) + b * (BSTR / 2) + rem * 2;
            dst[0] = pack2(v.x, v.y);
            dst[1] = pack2(v.z, v.w);
        }
        __syncthreads();

        // gx prologue for t=0 of this chunk
        f32x4 gx;
        {
            const half8 B2 = *reinterpret_cast<const half8*>(xrowbase);
            gx = __builtin_amdgcn_mfma_f32_16x16x32_f16(A2, B2, biasf, 0, 0, 0);
        }

        for (int t = 0; t < TCH; t++) {
            // B1: slot 8q+j = h of unit 6q+j, batch n (j written by wave j)
            const half8 B1 = *reinterpret_cast<const half8*>(&hx[bufp][cc][q][n][0]);
            // prefetch next step's x fragment (last iter: dummy index 0)
            const int tn = (t + 1 < TCH) ? t + 1 : 0;
            const half8 B2n = *reinterpret_cast<const half8*>(xrowbase + tn * xstep);

            f32x4 g = __builtin_amdgcn_mfma_f32_16x16x32_f16(A1, B1, gx, 0, 0, 0);
            gx = __builtin_amdgcn_mfma_f32_16x16x32_f16(A2, B2n, biasf, 0, 0, 0);

            // fused-denominator activations: 7 trans for this lane's cell
            //   c' = [c(1+Y)(1+Z) + (1+X)(Z-1)] * rcp((1+X)(1+Y)(1+Z))
            //   h  = (W-1) * rcp((1+V)(1+W)),  W = e^{2*min(c',18)}
            {
                const float Y  = exp2_fast(g[0] * -1.44269504f);  // i
                const float X  = exp2_fast(g[1] * -1.44269504f);  // f
                const float Z  = exp2_fast(g[2] *  2.88539008f);  // g
                const float V  = exp2_fast(g[3] * -1.44269504f);  // o
                const float ax = 1.0f + X;
                const float ay = 1.0f + Y;
                const float az = 1.0f + Z;
                const float num = c * ay * az + ax * (Z - 1.0f);
                const float cn  = num * rcp_fast(ax * ay * az);
                c = cn;
                const float W  = exp2_fast(fminf(cn, 18.0f) * 2.88539008f);
                hv = (W - 1.0f) * rcp_fast((1.0f + V) * (1.0f + W));
            }

            // publish own unit to the other buffer (ALL lanes; slots 6,7 untouched)
            hx[1 - bufp][cc][q][n][tau] = (_Float16)hv;
            bufp ^= 1;
            __syncthreads();
        }
    }

    // ---- epilogue: out[b][u] = b_lin[u] + sum_k tanh(h[k]) * W_lin[u][k] ----
    thbuf[cc][n][6 * q + tau] = tanh_f(hv);
    __syncthreads();

    {
        const int u = 6 * q + tau;
        const float* wl = &W_lin[u * 24];
        float acc = b_lin[u];
        #pragma unroll
        for (int k = 0; k < 24; k++) acc = fmaf(thbuf[cc][n][k], wl[k], acc);
        out[(size_t)batch * 24 + u] = acc;
    }
}

extern "C" void kernel_launch(void* const* d_in, const int* in_sizes, int n_in,
                              void* d_out, int out_size, void* d_ws, size_t ws_size,
                              hipStream_t stream) {
    const float* x     = (const float*)d_in[0];
    const float* W_ih  = (const float*)d_in[1];
    const float* W_hh  = (const float*)d_in[2];
    const float* b_ih  = (const float*)d_in[3];
    const float* b_hh  = (const float*)d_in[4];
    const float* W_lin = (const float*)d_in[5];
    const float* b_lin = (const float*)d_in[6];
    float* out = (float*)d_out;

    const int B = in_sizes[0] / (T_STEPS * P_FEAT);   // 8192
    dim3 grid(B / NB), block(768);                    // 256 blocks x 12 waves
    lstm_6t<<<grid, block, 0, stream>>>(x, W_ih, W_hh, b_ih, b_hh, W_lin, b_lin, out);
}